// Round 11
// baseline (306.895 us; speedup 1.0000x reference)
//
#include <hip/hip_runtime.h>

#define HIDDEN 128
#define N_RAYS 65536
#define NEAR_D 0.01f
#define FAR_D 10.0f
#define MAX_ITERS 32

typedef _Float16 f16x8 __attribute__((ext_vector_type(8)));
typedef __fp16 fp16x2 __attribute__((ext_vector_type(2)));   // cvt_pkrtz result type
typedef float f32x16 __attribute__((ext_vector_type(16)));

// DPP-assisted add: v + (v shifted by CTRL).
template <int CTRL, int ROW_MASK>
__device__ __forceinline__ float dpp_add(float v) {
    int s = __builtin_amdgcn_update_dpp(0, __float_as_int(v), CTRL, ROW_MASK, 0xF, true);
    return v + __int_as_float(s);
}
// Sum over each 32-lane half; result lands in lane 31 (half 0) / lane 63 (half 1).
__device__ __forceinline__ float half_sum_dpp(float v) {
    v = dpp_add<0x111, 0xF>(v);   // row_shr:1
    v = dpp_add<0x112, 0xF>(v);   // row_shr:2
    v = dpp_add<0x114, 0xF>(v);   // row_shr:4
    v = dpp_add<0x118, 0xF>(v);   // row_shr:8  -> lanes 15/31/47/63 hold 16-sums
    v = dpp_add<0x142, 0xA>(v);   // row_bcast15 -> lanes 31/63 hold 32-sums
    return v;
}

// ---------------------------------------------------------------------------
// Prologue: W2 B-operand fragment image (fp16 hi limb | lo limb).
//   img[l*16384 + (t*8+c)*512 + L*8 + j] == limb_l( W2[k][n] ),
//   n = t*32 + (L&31),  k = c*16 + ((L>>5)&1)*8 + j.
// ---------------------------------------------------------------------------
__global__ void w2_frag_kernel(const float* __restrict__ W2,
                               _Float16* __restrict__ img) {
    int tid = blockIdx.x * blockDim.x + threadIdx.x;   // 0..16383
    int j = tid & 7;
    int L = (tid >> 3) & 63;
    int tc = tid >> 9;
    int t = tc >> 3, c = tc & 7;
    int n = t * 32 + (L & 31);
    int k = c * 16 + ((L >> 5) & 1) * 8 + j;
    float w = W2[k * HIDDEN + n];
    _Float16 hi = (_Float16)w;
    _Float16 lo = (_Float16)(w - (float)hi);
    img[tid] = hi;
    img[16384 + tid] = lo;
}

// ---------------------------------------------------------------------------
// R21 = R19 (best, 246 us, absmax 4.8e-7) + SCHEDULING ONLY (bit-identical):
// R20 proved 3-limb is the precision floor (dropping Bl -> absmax 0.59).
// R19 books: per wave-iter window ~15.4K cyc = 3.1K MFMA + ~1.5K VALU +
// ~10K exposed stall. Suspect: t-sequential MFMA order issues 3 back-to-back
// dependent MFMAs on the same acc (in-order stall ~32cy each, ~8/chunk).
//   (a) limb-major round-robin: pass Ah*B[0..3]h, Ah*B[0..3]l, Al*B[0..3]h
//       -> same-acc MFMAs spaced 4 apart; per-acc chain order PRESERVED.
//   (b) depth-1 B-frag prefetch: chunk c+1's 8 ds_reads issue before chunk
//       c's MFMA block (LDS gets ~400cy to return under the MFMAs).
// ---------------------------------------------------------------------------
__launch_bounds__(256, 2)
__global__ void sphere_trace_kernel(
    const float* __restrict__ origins,
    const float* __restrict__ directions,
    const float* __restrict__ W1,    // [3][128]
    const float* __restrict__ b1,    // [128]
    const _Float16* __restrict__ w2img, // 32768 halfs (hi | lo)
    const float* __restrict__ b2,    // [128]
    const float* __restrict__ W3,    // [128]
    const float* __restrict__ b3,    // [1]
    const float* __restrict__ Wc1,   // [3][128]
    const float* __restrict__ bc1,   // [128]
    const float* __restrict__ Wc2,   // [128][3]
    const float* __restrict__ bc2,   // [3]
    float* __restrict__ out)         // [N][3]
{
    __shared__ __align__(16) _Float16 wlds[32768];   // 64 KB fragment image
    __shared__ __align__(16) float4 w1s[128];        // 2 KB: {W1x,W1y,W1z,b1}/k
    __shared__ float sbuf[4][32];                    // per-wave s exchange

    const int tid = threadIdx.x;
    const int lane = tid & 63;
    const int w = __builtin_amdgcn_readfirstlane(tid >> 6);
    const int q = lane >> 5;           // half-wave id
    const int n32 = lane & 31;         // N-column within tile / ray id

    // ---- stage fragment image + W1 pack into LDS (only __syncthreads here)
    {
        const float4* src = (const float4*)w2img;
        float4* dst = (float4*)wlds;
        #pragma unroll
        for (int i = 0; i < 16; ++i)
            dst[tid + 256 * i] = src[tid + 256 * i];
        if (tid < 128) {
            float4 wv;
            wv.x = W1[tid];
            wv.y = W1[HIDDEN + tid];
            wv.z = W1[2 * HIDDEN + tid];
            wv.w = b1[tid];
            w1s[tid] = wv;
        }
    }
    __syncthreads();

    // ---- ray state: ALL 64 lanes hold ray (lane&31)'s state (hi mirrors lo)
    const int ray = blockIdx.x * 128 + w * 32 + n32;
    float px = origins[ray * 3 + 0];
    float py = origins[ray * 3 + 1];
    float pz = origins[ray * 3 + 2];
    const float dx = directions[ray * 3 + 0];
    const float dy = directions[ray * 3 + 1];
    const float dz = directions[ray * 3 + 2];
    float dist = 0.0f;
    bool frozen = false;

    // ---- per-lane epilogue constants (4 output columns n = t*32 + n32)
    float b2v[4], w3v[4];
    #pragma unroll
    for (int t = 0; t < 4; ++t) {
        b2v[t] = b2[t * 32 + n32];
        w3v[t] = W3[t * 32 + n32];
    }
    const float b3v = b3[0];
    const int q8 = q * 8;

    #pragma unroll 1
    for (int it = 0; it < MAX_ITERS; ++it) {
        const float ppx = px, ppy = py, ppz = pz;

        // layer-1 for one 8-k group: unscaled, packed-f16 hi/lo limb split
        auto layer1 = [&](int kb, f16x8& Ah, f16x8& Al) {
            union { f16x8 v; fp16x2 p[4]; } uh, ul;
            #pragma unroll
            for (int jp = 0; jp < 4; ++jp) {
                const float4 w0 = w1s[kb + 2 * jp];
                const float4 w1v = w1s[kb + 2 * jp + 1];
                const float x0 = fmaxf(
                    fmaf(ppx, w0.x, fmaf(ppy, w0.y, fmaf(ppz, w0.z, w0.w))), 0.0f);
                const float x1 = fmaxf(
                    fmaf(ppx, w1v.x, fmaf(ppy, w1v.y, fmaf(ppz, w1v.z, w1v.w))), 0.0f);
                const fp16x2 hi = __builtin_amdgcn_cvt_pkrtz(x0, x1);
                const float l0 = x0 - (float)hi[0];
                const float l1 = x1 - (float)hi[1];
                uh.p[jp] = hi;
                ul.p[jp] = __builtin_amdgcn_cvt_pkrtz(l0, l1);
            }
            Ah = uh.v; Al = ul.v;
        };

        // ---- layer 2: chunk-outer loop, depth-1 pipeline on A AND B frags.
        // acc starts at b2 (C = b2 + A*B).
        f32x16 acc[4];
        #pragma unroll
        for (int t = 0; t < 4; ++t)
            #pragma unroll
            for (int r = 0; r < 16; ++r) acc[t][r] = b2v[t];

        // preload chunk 0: B-frags + A-frags
        const int lb = lane << 3;
        f16x8 B0h = *(const f16x8*)(wlds + lb);
        f16x8 B0l = *(const f16x8*)(wlds + 16384 + lb);
        f16x8 B1h = *(const f16x8*)(wlds + lb + (1 << 12));
        f16x8 B1l = *(const f16x8*)(wlds + 16384 + lb + (1 << 12));
        f16x8 B2h = *(const f16x8*)(wlds + lb + (2 << 12));
        f16x8 B2l = *(const f16x8*)(wlds + 16384 + lb + (2 << 12));
        f16x8 B3h = *(const f16x8*)(wlds + lb + (3 << 12));
        f16x8 B3l = *(const f16x8*)(wlds + 16384 + lb + (3 << 12));
        f16x8 Ah, Al, AhN, AlN;
        layer1(q8, Ah, Al);

        #pragma unroll 1
        for (int c = 0; c < 8; ++c) {
            // prefetch chunk c+1 (B-frags + layer1) before chunk c's MFMAs
            f16x8 N0h, N0l, N1h, N1l, N2h, N2l, N3h, N3l;
            if (c < 7) {
                const int nb = ((c + 1) << 9) + lb;
                N0h = *(const f16x8*)(wlds + nb);
                N0l = *(const f16x8*)(wlds + 16384 + nb);
                N1h = *(const f16x8*)(wlds + nb + (1 << 12));
                N1l = *(const f16x8*)(wlds + 16384 + nb + (1 << 12));
                N2h = *(const f16x8*)(wlds + nb + (2 << 12));
                N2l = *(const f16x8*)(wlds + 16384 + nb + (2 << 12));
                N3h = *(const f16x8*)(wlds + nb + (3 << 12));
                N3l = *(const f16x8*)(wlds + 16384 + nb + (3 << 12));
                layer1((c + 1) * 16 + q8, AhN, AlN);
            }

            // 12 MFMAs, limb-major round-robin across tiles; per-acc chain
            // order (Ah*Bh -> Ah*Bl -> Al*Bh) preserved, spaced 4 apart.
            __builtin_amdgcn_s_setprio(1);
            acc[0] = __builtin_amdgcn_mfma_f32_32x32x16_f16(Ah, B0h, acc[0], 0, 0, 0);
            acc[1] = __builtin_amdgcn_mfma_f32_32x32x16_f16(Ah, B1h, acc[1], 0, 0, 0);
            acc[2] = __builtin_amdgcn_mfma_f32_32x32x16_f16(Ah, B2h, acc[2], 0, 0, 0);
            acc[3] = __builtin_amdgcn_mfma_f32_32x32x16_f16(Ah, B3h, acc[3], 0, 0, 0);
            acc[0] = __builtin_amdgcn_mfma_f32_32x32x16_f16(Ah, B0l, acc[0], 0, 0, 0);
            acc[1] = __builtin_amdgcn_mfma_f32_32x32x16_f16(Ah, B1l, acc[1], 0, 0, 0);
            acc[2] = __builtin_amdgcn_mfma_f32_32x32x16_f16(Ah, B2l, acc[2], 0, 0, 0);
            acc[3] = __builtin_amdgcn_mfma_f32_32x32x16_f16(Ah, B3l, acc[3], 0, 0, 0);
            acc[0] = __builtin_amdgcn_mfma_f32_32x32x16_f16(Al, B0h, acc[0], 0, 0, 0);
            acc[1] = __builtin_amdgcn_mfma_f32_32x32x16_f16(Al, B1h, acc[1], 0, 0, 0);
            acc[2] = __builtin_amdgcn_mfma_f32_32x32x16_f16(Al, B2h, acc[2], 0, 0, 0);
            acc[3] = __builtin_amdgcn_mfma_f32_32x32x16_f16(Al, B3h, acc[3], 0, 0, 0);
            __builtin_amdgcn_s_setprio(0);

            if (c < 7) {
                B0h = N0h; B0l = N0l; B1h = N1h; B1l = N1l;
                B2h = N2h; B2l = N2l; B3h = N3h; B3l = N3l;
                Ah = AhN; Al = AlN;
            }
        }

        // ---- epilogue: relu (b2 already inside acc), dot W3
        float ps[16];
        #pragma unroll
        for (int r = 0; r < 16; ++r) ps[r] = 0.0f;
        #pragma unroll
        for (int t = 0; t < 4; ++t) {
            #pragma unroll
            for (int r = 0; r < 16; ++r) {
                const float v = fmaxf(acc[t][r], 0.0f);
                ps[r] = fmaf(v, w3v[t], ps[r]);
            }
        }

        // ---- 32-lane reduction on the VALU pipe (DPP); sums in lanes 31/63
        #pragma unroll
        for (int r = 0; r < 16; ++r)
            ps[r] = half_sum_dpp(ps[r]);
        if ((lane & 31) == 31) {
            const int mb = q * 4;      // q=0 -> rows 8g..8g+3; q=1 -> 8g+4..8g+7
            #pragma unroll
            for (int g = 0; g < 4; ++g) {
                float4 v4;
                v4.x = ps[4 * g + 0];
                v4.y = ps[4 * g + 1];
                v4.z = ps[4 * g + 2];
                v4.w = ps[4 * g + 3];
                *(float4*)&sbuf[w][8 * g + mb] = v4;
            }
        }
        // all lanes read their ray's s (hi lanes mirror lo lanes)
        const float s = sbuf[w][n32] + b3v;

        // ---- march (exact reference semantics), duplicated on both halves
        {
            const bool valid = (s <= NEAR_D) && (dist < FAR_D);
            if (!frozen) {
                if (valid) {
                    frozen = true;
                } else {
                    dist += s;
                    px = fmaf(dx, s, px);
                    py = fmaf(dy, s, py);
                    pz = fmaf(dz, s, pz);
                }
            }
        }
        if (__ballot((lane < 32) && !frozen) == 0) break;
    }

    // ---- color MLP (once): lane owns hidden units lane, lane+64
    const int k0 = lane, k1 = lane + 64;
    const float cx0 = Wc1[k0], cx1 = Wc1[k1];
    const float cy0 = Wc1[HIDDEN + k0], cy1 = Wc1[HIDDEN + k1];
    const float cz0 = Wc1[2 * HIDDEN + k0], cz1 = Wc1[2 * HIDDEN + k1];
    const float cb0 = bc1[k0], cb1 = bc1[k1];
    const float u00 = Wc2[k0 * 3 + 0], u01 = Wc2[k0 * 3 + 1], u02 = Wc2[k0 * 3 + 2];
    const float u10 = Wc2[k1 * 3 + 0], u11 = Wc2[k1 * 3 + 1], u12 = Wc2[k1 * 3 + 2];

    float g0 = 0.f, g1 = 0.f, g2 = 0.f;
    #pragma unroll 1
    for (int m = 0; m < 32; ++m) {
        const float qx = __shfl(px, m);
        const float qy = __shfl(py, m);
        const float qz = __shfl(pz, m);
        const float h0 = fmaxf(fmaf(qx, cx0, fmaf(qy, cy0, fmaf(qz, cz0, cb0))), 0.f);
        const float h1 = fmaxf(fmaf(qx, cx1, fmaf(qy, cy1, fmaf(qz, cz1, cb1))), 0.f);
        float a0 = fmaf(h0, u00, h1 * u10);
        float a1 = fmaf(h0, u01, h1 * u11);
        float a2 = fmaf(h0, u02, h1 * u12);
        #pragma unroll
        for (int mask = 1; mask < 64; mask <<= 1) {
            a0 += __shfl_xor(a0, mask);
            a1 += __shfl_xor(a1, mask);
            a2 += __shfl_xor(a2, mask);
        }
        if (lane == m) { g0 = a0; g1 = a1; g2 = a2; }
    }

    if (lane < 32) {
        float c0 = 0.f, c1 = 0.f, c2 = 0.f;
        if (frozen || dist < FAR_D) {
            c0 = 1.0f / (1.0f + __expf(-(g0 + bc2[0])));
            c1 = 1.0f / (1.0f + __expf(-(g1 + bc2[1])));
            c2 = 1.0f / (1.0f + __expf(-(g2 + bc2[2])));
        }
        out[ray * 3 + 0] = c0;
        out[ray * 3 + 1] = c1;
        out[ray * 3 + 2] = c2;
    }
}

extern "C" void kernel_launch(void* const* d_in, const int* in_sizes, int n_in,
                              void* d_out, int out_size, void* d_ws, size_t ws_size,
                              hipStream_t stream) {
    const float* origins    = (const float*)d_in[0];
    const float* directions = (const float*)d_in[1];
    const float* W1  = (const float*)d_in[2];
    const float* b1  = (const float*)d_in[3];
    const float* W2  = (const float*)d_in[4];
    const float* b2  = (const float*)d_in[5];
    const float* W3  = (const float*)d_in[6];
    const float* b3  = (const float*)d_in[7];
    const float* Wc1 = (const float*)d_in[8];
    const float* bc1 = (const float*)d_in[9];
    const float* Wc2 = (const float*)d_in[10];
    const float* bc2 = (const float*)d_in[11];
    float* out = (float*)d_out;

    _Float16* w2img = (_Float16*)d_ws;   // 64 KB fragment image

    w2_frag_kernel<<<64, 256, 0, stream>>>(W2, w2img);

    sphere_trace_kernel<<<N_RAYS / 128, 256, 0, stream>>>(
        origins, directions, W1, b1, w2img, b2, W3, b3,
        Wc1, bc1, Wc2, bc2, out);
}

// Round 12
// 296.696 us; speedup vs baseline: 1.0344x; 1.0344x over previous
//
#include <hip/hip_runtime.h>

#define HIDDEN 128
#define N_RAYS 65536
#define NEAR_D 0.01f
#define FAR_D 10.0f
#define MAX_ITERS 32

typedef _Float16 f16x8 __attribute__((ext_vector_type(8)));
typedef __fp16 fp16x2 __attribute__((ext_vector_type(2)));   // cvt_pkrtz result type
typedef float f32x16 __attribute__((ext_vector_type(16)));

// DPP-assisted add: v + (v shifted by CTRL).
template <int CTRL, int ROW_MASK>
__device__ __forceinline__ float dpp_add(float v) {
    int s = __builtin_amdgcn_update_dpp(0, __float_as_int(v), CTRL, ROW_MASK, 0xF, true);
    return v + __int_as_float(s);
}
// Sum over each 32-lane half; result lands in lane 31 (half 0) / lane 63 (half 1).
__device__ __forceinline__ float half_sum_dpp(float v) {
    v = dpp_add<0x111, 0xF>(v);   // row_shr:1
    v = dpp_add<0x112, 0xF>(v);   // row_shr:2
    v = dpp_add<0x114, 0xF>(v);   // row_shr:4
    v = dpp_add<0x118, 0xF>(v);   // row_shr:8  -> lanes 15/31/47/63 hold 16-sums
    v = dpp_add<0x142, 0xA>(v);   // row_bcast15 -> lanes 31/63 hold 32-sums
    return v;
}

// ---------------------------------------------------------------------------
// R22 = R19 (best: 246 us rocprof / 292.8 bench, absmax 4.8e-7) + FUSED
// PROLOGUE. R21 (round-robin + deep prefetch) regressed -> CDNA4 forwards
// same-acc MFMA chains; the compiler's R19 schedule is the fixed point, and
// the kernel body is at its compute roofline: MFMA-pipe busy 38.4% x 246 us
// = 95 us == all-2048-waves x 32 iters x 96 MFMAs (no early exit exists:
// reference semantics march "miss" rays to iter 32). MFMA count is
// precision-irreducible (R20: dropping one limb -> absmax 0.59 FAIL).
// Remaining slack was OUTSIDE the body: bench 292.8 vs dispatch 246.4 =
// ~46 us of prologue-kernel + gap + launch overhead. R22 computes the W2
// fragment image in-kernel during LDS staging (same index math, same RTN
// casts -> bit-identical image; W2 reads are L2-resident and half-wave
// coalesced), deleting the second kernel and the workspace roundtrip.
// ---------------------------------------------------------------------------
__launch_bounds__(256, 2)
__global__ void sphere_trace_kernel(
    const float* __restrict__ origins,
    const float* __restrict__ directions,
    const float* __restrict__ W1,    // [3][128]
    const float* __restrict__ b1,    // [128]
    const float* __restrict__ W2,    // [128][128]
    const float* __restrict__ b2,    // [128]
    const float* __restrict__ W3,    // [128]
    const float* __restrict__ b3,    // [1]
    const float* __restrict__ Wc1,   // [3][128]
    const float* __restrict__ bc1,   // [128]
    const float* __restrict__ Wc2,   // [128][3]
    const float* __restrict__ bc2,   // [3]
    float* __restrict__ out)         // [N][3]
{
    __shared__ __align__(16) _Float16 wlds[32768];   // 64 KB fragment image
    __shared__ __align__(16) float4 w1s[128];        // 2 KB: {W1x,W1y,W1z,b1}/k
    __shared__ float sbuf[4][32];                    // per-wave s exchange

    const int tid = threadIdx.x;
    const int lane = tid & 63;
    const int w = __builtin_amdgcn_readfirstlane(tid >> 6);
    const int q = lane >> 5;           // half-wave id
    const int n32 = lane & 31;         // N-column within tile / ray id

    // ---- stage: build fragment image from W2 directly (bit-identical to the
    // old w2_frag_kernel: same index math, same RTN casts), + W1 pack.
    //   wlds[g*8+j]        = (f16) W2[k][n]            (hi limb)
    //   wlds[16384+g*8+j]  = (f16)(W2[k][n] - hi)      (lo limb)
    //   g = (t*8+c)*64 + L, n = t*32+(L&31), k = c*16+((L>>5)&1)*8+j.
    {
        #pragma unroll
        for (int i = 0; i < 8; ++i) {
            const int g = tid + 256 * i;          // fragment row 0..2047
            const int L = g & 63;
            const int tc = g >> 6;                // 0..31
            const int t = tc >> 3, c = tc & 7;
            const int n = t * 32 + (L & 31);
            const int kb = c * 16 + ((L >> 5) & 1) * 8;
            f16x8 hi8, lo8;
            #pragma unroll
            for (int j = 0; j < 8; ++j) {
                const float wv = W2[(kb + j) * HIDDEN + n];
                const _Float16 h = (_Float16)wv;
                hi8[j] = h;
                lo8[j] = (_Float16)(wv - (float)h);
            }
            *(f16x8*)(wlds + g * 8) = hi8;
            *(f16x8*)(wlds + 16384 + g * 8) = lo8;
        }
        if (tid < 128) {
            float4 wv;
            wv.x = W1[tid];
            wv.y = W1[HIDDEN + tid];
            wv.z = W1[2 * HIDDEN + tid];
            wv.w = b1[tid];
            w1s[tid] = wv;
        }
    }
    __syncthreads();

    // ---- ray state: ALL 64 lanes hold ray (lane&31)'s state (hi mirrors lo)
    const int ray = blockIdx.x * 128 + w * 32 + n32;
    float px = origins[ray * 3 + 0];
    float py = origins[ray * 3 + 1];
    float pz = origins[ray * 3 + 2];
    const float dx = directions[ray * 3 + 0];
    const float dy = directions[ray * 3 + 1];
    const float dz = directions[ray * 3 + 2];
    float dist = 0.0f;
    bool frozen = false;

    // ---- per-lane epilogue constants (4 output columns n = t*32 + n32)
    float b2v[4], w3v[4];
    #pragma unroll
    for (int t = 0; t < 4; ++t) {
        b2v[t] = b2[t * 32 + n32];
        w3v[t] = W3[t * 32 + n32];
    }
    const float b3v = b3[0];
    const int q8 = q * 8;

    #pragma unroll 1
    for (int it = 0; it < MAX_ITERS; ++it) {
        const float ppx = px, ppy = py, ppz = pz;

        // layer-1 for one 8-k group: unscaled, packed-f16 hi/lo limb split
        auto layer1 = [&](int kb, f16x8& Ah, f16x8& Al) {
            union { f16x8 v; fp16x2 p[4]; } uh, ul;
            #pragma unroll
            for (int jp = 0; jp < 4; ++jp) {
                const float4 w0 = w1s[kb + 2 * jp];
                const float4 w1v = w1s[kb + 2 * jp + 1];
                const float x0 = fmaxf(
                    fmaf(ppx, w0.x, fmaf(ppy, w0.y, fmaf(ppz, w0.z, w0.w))), 0.0f);
                const float x1 = fmaxf(
                    fmaf(ppx, w1v.x, fmaf(ppy, w1v.y, fmaf(ppz, w1v.z, w1v.w))), 0.0f);
                const fp16x2 hi = __builtin_amdgcn_cvt_pkrtz(x0, x1);
                const float l0 = x0 - (float)hi[0];
                const float l1 = x1 - (float)hi[1];
                uh.p[jp] = hi;
                ul.p[jp] = __builtin_amdgcn_cvt_pkrtz(l0, l1);
            }
            Ah = uh.v; Al = ul.v;
        };

        // ---- layer 2: chunk-outer loop, depth-1 pipeline on A-fragments.
        // acc starts at b2 (C = b2 + A*B).
        f32x16 acc[4];
        #pragma unroll
        for (int t = 0; t < 4; ++t)
            #pragma unroll
            for (int r = 0; r < 16; ++r) acc[t][r] = b2v[t];

        f16x8 Ah, Al, AhN, AlN;
        layer1(q8, Ah, Al);                   // chunk 0

        #pragma unroll 1
        for (int c = 0; c < 8; ++c) {
            // issue chunk c's B-frag ds_reads (named vars, static t indices)
            const int base = (c << 9) + (lane << 3);
            const f16x8 b0h = *(const f16x8*)(wlds + base);
            const f16x8 b0l = *(const f16x8*)(wlds + 16384 + base);
            const f16x8 b1h = *(const f16x8*)(wlds + base + (1 << 12));
            const f16x8 b1l = *(const f16x8*)(wlds + 16384 + base + (1 << 12));
            const f16x8 b2h = *(const f16x8*)(wlds + base + (2 << 12));
            const f16x8 b2l = *(const f16x8*)(wlds + 16384 + base + (2 << 12));
            const f16x8 b3h = *(const f16x8*)(wlds + base + (3 << 12));
            const f16x8 b3l = *(const f16x8*)(wlds + 16384 + base + (3 << 12));

            // chunk c+1 layer-1 VALU burst overlaps the ds_read latency
            if (c < 7) layer1((c + 1) * 16 + q8, AhN, AlN);

            // 12 MFMAs, t-sequential; per-acc order (Ah*Bh, Ah*Bl, Al*Bh)
            __builtin_amdgcn_s_setprio(1);
            acc[0] = __builtin_amdgcn_mfma_f32_32x32x16_f16(Ah, b0h, acc[0], 0, 0, 0);
            acc[0] = __builtin_amdgcn_mfma_f32_32x32x16_f16(Ah, b0l, acc[0], 0, 0, 0);
            acc[0] = __builtin_amdgcn_mfma_f32_32x32x16_f16(Al, b0h, acc[0], 0, 0, 0);
            acc[1] = __builtin_amdgcn_mfma_f32_32x32x16_f16(Ah, b1h, acc[1], 0, 0, 0);
            acc[1] = __builtin_amdgcn_mfma_f32_32x32x16_f16(Ah, b1l, acc[1], 0, 0, 0);
            acc[1] = __builtin_amdgcn_mfma_f32_32x32x16_f16(Al, b1h, acc[1], 0, 0, 0);
            acc[2] = __builtin_amdgcn_mfma_f32_32x32x16_f16(Ah, b2h, acc[2], 0, 0, 0);
            acc[2] = __builtin_amdgcn_mfma_f32_32x32x16_f16(Ah, b2l, acc[2], 0, 0, 0);
            acc[2] = __builtin_amdgcn_mfma_f32_32x32x16_f16(Al, b2h, acc[2], 0, 0, 0);
            acc[3] = __builtin_amdgcn_mfma_f32_32x32x16_f16(Ah, b3h, acc[3], 0, 0, 0);
            acc[3] = __builtin_amdgcn_mfma_f32_32x32x16_f16(Ah, b3l, acc[3], 0, 0, 0);
            acc[3] = __builtin_amdgcn_mfma_f32_32x32x16_f16(Al, b3h, acc[3], 0, 0, 0);
            __builtin_amdgcn_s_setprio(0);

            Ah = AhN; Al = AlN;
        }

        // ---- epilogue: relu (b2 already inside acc), dot W3
        float ps[16];
        #pragma unroll
        for (int r = 0; r < 16; ++r) ps[r] = 0.0f;
        #pragma unroll
        for (int t = 0; t < 4; ++t) {
            #pragma unroll
            for (int r = 0; r < 16; ++r) {
                const float v = fmaxf(acc[t][r], 0.0f);
                ps[r] = fmaf(v, w3v[t], ps[r]);
            }
        }

        // ---- 32-lane reduction on the VALU pipe (DPP); sums in lanes 31/63
        #pragma unroll
        for (int r = 0; r < 16; ++r)
            ps[r] = half_sum_dpp(ps[r]);
        if ((lane & 31) == 31) {
            const int mb = q * 4;      // q=0 -> rows 8g..8g+3; q=1 -> 8g+4..8g+7
            #pragma unroll
            for (int g = 0; g < 4; ++g) {
                float4 v4;
                v4.x = ps[4 * g + 0];
                v4.y = ps[4 * g + 1];
                v4.z = ps[4 * g + 2];
                v4.w = ps[4 * g + 3];
                *(float4*)&sbuf[w][8 * g + mb] = v4;
            }
        }
        // all lanes read their ray's s (hi lanes mirror lo lanes)
        const float s = sbuf[w][n32] + b3v;

        // ---- march (exact reference semantics), duplicated on both halves
        {
            const bool valid = (s <= NEAR_D) && (dist < FAR_D);
            if (!frozen) {
                if (valid) {
                    frozen = true;
                } else {
                    dist += s;
                    px = fmaf(dx, s, px);
                    py = fmaf(dy, s, py);
                    pz = fmaf(dz, s, pz);
                }
            }
        }
        if (__ballot((lane < 32) && !frozen) == 0) break;
    }

    // ---- color MLP (once): lane owns hidden units lane, lane+64
    const int k0 = lane, k1 = lane + 64;
    const float cx0 = Wc1[k0], cx1 = Wc1[k1];
    const float cy0 = Wc1[HIDDEN + k0], cy1 = Wc1[HIDDEN + k1];
    const float cz0 = Wc1[2 * HIDDEN + k0], cz1 = Wc1[2 * HIDDEN + k1];
    const float cb0 = bc1[k0], cb1 = bc1[k1];
    const float u00 = Wc2[k0 * 3 + 0], u01 = Wc2[k0 * 3 + 1], u02 = Wc2[k0 * 3 + 2];
    const float u10 = Wc2[k1 * 3 + 0], u11 = Wc2[k1 * 3 + 1], u12 = Wc2[k1 * 3 + 2];

    float g0 = 0.f, g1 = 0.f, g2 = 0.f;
    #pragma unroll 1
    for (int m = 0; m < 32; ++m) {
        const float qx = __shfl(px, m);
        const float qy = __shfl(py, m);
        const float qz = __shfl(pz, m);
        const float h0 = fmaxf(fmaf(qx, cx0, fmaf(qy, cy0, fmaf(qz, cz0, cb0))), 0.f);
        const float h1 = fmaxf(fmaf(qx, cx1, fmaf(qy, cy1, fmaf(qz, cz1, cb1))), 0.f);
        float a0 = fmaf(h0, u00, h1 * u10);
        float a1 = fmaf(h0, u01, h1 * u11);
        float a2 = fmaf(h0, u02, h1 * u12);
        #pragma unroll
        for (int mask = 1; mask < 64; mask <<= 1) {
            a0 += __shfl_xor(a0, mask);
            a1 += __shfl_xor(a1, mask);
            a2 += __shfl_xor(a2, mask);
        }
        if (lane == m) { g0 = a0; g1 = a1; g2 = a2; }
    }

    if (lane < 32) {
        float c0 = 0.f, c1 = 0.f, c2 = 0.f;
        if (frozen || dist < FAR_D) {
            c0 = 1.0f / (1.0f + __expf(-(g0 + bc2[0])));
            c1 = 1.0f / (1.0f + __expf(-(g1 + bc2[1])));
            c2 = 1.0f / (1.0f + __expf(-(g2 + bc2[2])));
        }
        out[ray * 3 + 0] = c0;
        out[ray * 3 + 1] = c1;
        out[ray * 3 + 2] = c2;
    }
}

extern "C" void kernel_launch(void* const* d_in, const int* in_sizes, int n_in,
                              void* d_out, int out_size, void* d_ws, size_t ws_size,
                              hipStream_t stream) {
    const float* origins    = (const float*)d_in[0];
    const float* directions = (const float*)d_in[1];
    const float* W1  = (const float*)d_in[2];
    const float* b1  = (const float*)d_in[3];
    const float* W2  = (const float*)d_in[4];
    const float* b2  = (const float*)d_in[5];
    const float* W3  = (const float*)d_in[6];
    const float* b3  = (const float*)d_in[7];
    const float* Wc1 = (const float*)d_in[8];
    const float* bc1 = (const float*)d_in[9];
    const float* Wc2 = (const float*)d_in[10];
    const float* bc2 = (const float*)d_in[11];
    float* out = (float*)d_out;

    sphere_trace_kernel<<<N_RAYS / 128, 256, 0, stream>>>(
        origins, directions, W1, b1, W2, b2, W3, b3,
        Wc1, bc1, Wc2, bc2, out);
}